// Round 6
// baseline (372.448 us; speedup 1.0000x reference)
//
#include <hip/hip_runtime.h>

#define DI __device__ __forceinline__

using floatx4 = __attribute__((ext_vector_type(4))) float;
using bf16x8  = __attribute__((ext_vector_type(8))) short;
using bf16x4  = __attribute__((ext_vector_type(4))) short;
using uintx4  = __attribute__((ext_vector_type(4))) unsigned int;

constexpr int T_STEPS = 16384;
constexpr int NN      = 97;
constexpr int M_TOT   = T_STEPS * 6;   // 98304 rows of the (t,h) x channel matrices
constexpr int CHUNK   = 16;            // stored steps per chunk
constexpr int WARM    = 12;            // warm-up steps
constexpr int NCHUNK  = T_STEPS / CHUNK;   // 1024 chunks; paired 2-per-block -> 512 blocks

// ---------------- ws layout (bytes, all 256B aligned) ----------------
constexpr size_t AL_OFF = 0;                  constexpr size_t AL_SZ = (size_t)M_TOT*128*2; // al: [M][128] bf16 (97 used, zero-pad)
constexpr size_t F1_OFF = AL_OFF + AL_SZ;     constexpr size_t F1_SZ = (size_t)M_TOT*224*2; // f1: [M][224] bf16 (194 used)
constexpr size_t F2_OFF = F1_OFF + F1_SZ;     constexpr size_t F2_SZ = F1_SZ;
constexpr size_t F3_OFF = F2_OFF + F2_SZ;     constexpr size_t F3_SZ = (size_t)M_TOT*112*2; // f3: [M][112] bf16 (97 used)
constexpr size_t W1_OFF = F3_OFF + F3_SZ;     constexpr size_t W1_SZ = (size_t)3*224*128*2;
constexpr size_t W2_OFF = W1_OFF + W1_SZ;     constexpr size_t W2_SZ = (size_t)3*224*224*2;
constexpr size_t W3_OFF = W2_OFF + W2_SZ;     constexpr size_t W3_SZ = (size_t)3*112*224*2;
constexpr size_t B1_OFF = W3_OFF + W3_SZ;
constexpr size_t B2_OFF = B1_OFF + 1024;
constexpr size_t B3_OFF = B2_OFF + 1024;
constexpr size_t ST_OFF = B3_OFF + 1024;      // stats: [0..96]=sum, [128..224]=sumsq
constexpr size_t WH_OFF = ST_OFF + 1024;      // packed f16 Whh: 72 u32 (288 B)
// xp (f16 [T][97][24] = 76.3 MB) aliased onto f1+f2 (177 MB): dead before conv1 writes f1.
// Reads 1 row past T (prefetch) and up to 12 rows before 0 (block-0 warm; lands in
// zeroed al region) -- both inside ws, values discarded.
constexpr size_t XP_OFF = F1_OFF;

DI short f2bf(float f){
    union { float f; unsigned u; } a; a.f = f;
    unsigned r = (a.u + 0x7FFFu + ((a.u >> 16) & 1u)) >> 16;
    return (short)r;
}
DI float bf2f(short s){
    union { unsigned u; float f; } a; a.u = ((unsigned)(unsigned short)s) << 16;
    return a.f;
}
DI short f2h(float f){
    _Float16 h = (_Float16)f;
    return __builtin_bit_cast(short, h);
}
DI float h2f_lo(unsigned u){
    _Float16 x = __builtin_bit_cast(_Float16, (unsigned short)(u & 0xffffu));
    return (float)x;
}
DI float h2f_hi(unsigned u){
    _Float16 x = __builtin_bit_cast(_Float16, (unsigned short)(u >> 16));
    return (float)x;
}
DI float fsig(float x){
    float e = __builtin_amdgcn_exp2f(x * -1.442695041f);
    return __builtin_amdgcn_rcpf(1.0f + e);
}
DI float ftanh(float x){
    float e = __builtin_amdgcn_exp2f(x * 2.885390082f);   // exp(2x)
    return 1.0f - 2.0f * __builtin_amdgcn_rcpf(e + 1.0f); // graceful at +-inf
}

// acc += f16(lo half of SGPR w) * h   -- weight stays in an SGPR, zero VGPR cost
DI float mixlo(unsigned w, float h, float acc){
    asm("v_fma_mix_f32 %0, %1, %2, %0 op_sel:[0,0,0] op_sel_hi:[1,0,0]"
        : "+v"(acc) : "s"(w), "v"(h));
    return acc;
}
// acc += f16(hi half of SGPR w) * h
DI float mixhi(unsigned w, float h, float acc){
    asm("v_fma_mix_f32 %0, %1, %2, %0 op_sel:[1,0,0] op_sel_hi:[1,0,0]"
        : "+v"(acc) : "s"(w), "v"(h));
    return acc;
}

// async global->LDS, 16B per lane; LDS dest must be wave-uniform base + lane*16
DI void gload16(const void* g, void* l) {
    __builtin_amdgcn_global_load_lds(
        (const __attribute__((address_space(1))) unsigned int*)g,
        (__attribute__((address_space(3))) unsigned int*)l, 16, 0, 0);
}

// ---------------- weight repack (convs + packed-f16 Whh in one dispatch) ----------------
// conv layout: Wg[ks][kh][q][n][j]: k = ks*32 + q*8 + j (zero-padded), value = Wc[n][k][kh][kw=1]
DI void repack_one(const float* Wc, const float* bc, short* wdst, float* bdst,
                   int COUT, int CIN, int NT, int i)
{
    int j  = i & 7;
    int t1 = i >> 3;
    int n  = t1 % NT;
    int t2 = t1 / NT;
    int qq = t2 & 3;
    int t3 = t2 >> 2;
    int kh = t3 % 3;
    int ks = t3 / 3;
    int k  = ks*32 + qq*8 + j;
    float v = 0.f;
    if (n < COUT && k < CIN) v = Wc[((n*CIN + k)*3 + kh)*3 + 1]; // kw=1 only (W=1, pad=1)
    wdst[i] = f2bf(v);
    if (i < NT) bdst[i] = (i < COUT) ? bc[i] : 0.f;
}

constexpr int RT1 = 3*224*128;
constexpr int RT2 = RT1 + 3*224*224;
constexpr int RT3 = RT2 + 3*112*224;
constexpr int RT4 = RT3 + 72;          // 72 packed Whh words

__global__ __launch_bounds__(256) void repack_all(
    const float* __restrict__ Wc1, const float* __restrict__ bc1, short* __restrict__ w1, float* __restrict__ b1,
    const float* __restrict__ Wc2, const float* __restrict__ bc2, short* __restrict__ w2, float* __restrict__ b2,
    const float* __restrict__ Wc3, const float* __restrict__ bc3, short* __restrict__ w3, float* __restrict__ b3,
    const float* __restrict__ Whh, unsigned* __restrict__ wh)
{
    int idx = blockIdx.x*256 + threadIdx.x;
    if (idx < RT1)       repack_one(Wc1, bc1, w1, b1, 194,  97, 224, idx);
    else if (idx < RT2)  repack_one(Wc2, bc2, w2, b2, 194, 194, 224, idx - RT1);
    else if (idx < RT3)  repack_one(Wc3, bc3, w3, b3,  97, 194, 112, idx - RT2);
    else if (idx < RT4) {
        int i = idx - RT3;             // 0..71: g = gate row (0..23), dp = d-pair (0..2)
        int g = i / 3, dp = i - g*3;
        unsigned lo = (unsigned short)f2h(Whh[g*6 + 2*dp]);
        unsigned hi = (unsigned short)f2h(Whh[g*6 + 2*dp + 1]);
        wh[i] = lo | (hi << 16);
    }
}

// ---------------- x-projection: f16, plain gate order, LDS-staged coalesced stores ----
__global__ __launch_bounds__(256) void xproj_kernel(
    const float* __restrict__ X, const float* __restrict__ Wih,
    const float* __restrict__ bih, const float* __restrict__ bhh,
    short* __restrict__ xp)
{
    __shared__ alignas(16) short sbuf[256*24];      // 12 KB
    const int tid = threadIdx.x;
    const int idx = blockIdx.x*256 + tid;           // t*97+n, exactly T*97 threads
    const floatx4* xv = (const floatx4*)(X + (size_t)idx*12);
    floatx4 x0 = xv[0], x1 = xv[1], x2 = xv[2];
    float xr[12];
    #pragma unroll
    for (int f=0; f<4; ++f){ xr[f]=x0[f]; xr[4+f]=x1[f]; xr[8+f]=x2[f]; }

    short o24[24];
    #pragma unroll
    for (int g=0; g<24; ++g) {
        float s = bih[g] + bhh[g];
        #pragma unroll
        for (int f=0; f<12; ++f) s = fmaf(xr[f], Wih[g*12+f], s);
        o24[g] = f2h(s);                            // plain order: row g = Whh/bias row g
    }
    #pragma unroll
    for (int k=0; k<3; ++k)
        *(uintx4*)(&sbuf[tid*24 + k*8]) = *(const uintx4*)(&o24[k*8]);
    __syncthreads();
    const size_t base = (size_t)blockIdx.x * (256*24);
    #pragma unroll
    for (int k=0; k<3; ++k) {
        int off = k*2048 + tid*8;                   // shorts; 16B per lane, contiguous
        *(uintx4*)(xp + base + off) = *(const uintx4*)(&sbuf[off]);
    }
}

// ---------------- LSTM: 1 lane = 2 independent chains (ILP-2), SGPR f16 weights ----------
// Round-5 post-mortem: SGPR weights worked (SGPR=96) but 1 wave/SIMD + VGPR=36
// (collapsed prefetch, serialized j-groups) exposed ~2600cy/step of stall.
// Fix: in-wave ILP -- each lane runs chains (n, b) and (n, b+512) interleaved per
// hidden-unit group (jstep A then jstep B), so B's fma_mix issue fills A's
// transcendental latency under in-order issue. CHUNK=16 -> 512 paired blocks
// = 1024 waves = every SIMD occupied. Depth-1 prefetch/slot (~2800cy cover).
// Block-0 slot A warm reads rows -12..-1 = zeroed al region (valid ws); its h/c
// are hard-reset at s==0, so those steps are discarded -- no per-step guards.
DI float gateval(const unsigned* xw, int g){
    return (g & 1) ? h2f_hi(xw[g>>1]) : h2f_lo(xw[g>>1]);
}
DI void jstep(const unsigned* w, const unsigned* xw, int j,
              const float* h, float* hn, float* cs)
{
    float gi = gateval(xw, j);
    float gf = gateval(xw, 6+j);
    float gc = gateval(xw, 12+j);
    float go = gateval(xw, 18+j);
    #pragma unroll
    for (int dp=0; dp<3; ++dp){
        gi = mixlo(w[(j   )*3+dp], h[2*dp], gi); gi = mixhi(w[(j   )*3+dp], h[2*dp+1], gi);
        gf = mixlo(w[(6+j )*3+dp], h[2*dp], gf); gf = mixhi(w[(6+j )*3+dp], h[2*dp+1], gf);
        gc = mixlo(w[(12+j)*3+dp], h[2*dp], gc); gc = mixhi(w[(12+j)*3+dp], h[2*dp+1], gc);
        go = mixlo(w[(18+j)*3+dp], h[2*dp], go); go = mixhi(w[(18+j)*3+dp], h[2*dp+1], go);
    }
    float ig = fsig(gi), fg = fsig(gf), cg = ftanh(gc), og = fsig(go);
    cs[j] = fmaf(fg, cs[j], ig*cg);
    hn[j] = ftanh(og * ftanh(cs[j]));               // extra tanh, fed back (matches ref)
}

__global__ __launch_bounds__(128, 1) void lstm_kernel(
    const short* __restrict__ xp, const unsigned* __restrict__ wpk,
    short* __restrict__ al)
{
    const int n = threadIdx.x;
    if (n >= NN) return;
    const int b   = blockIdx.x;                     // 0..511
    const int tsA = b*CHUNK;
    const int tsB = (b + NCHUNK/2)*CHUNK;

    unsigned w[72];                                 // packed f16 pairs, wave-uniform -> SGPRs
    #pragma unroll
    for (int i=0; i<72; i+=4){
        uintx4 v = *(const uintx4*)(wpk + i);
        w[i+0] = __builtin_amdgcn_readfirstlane(v[0]);
        w[i+1] = __builtin_amdgcn_readfirstlane(v[1]);
        w[i+2] = __builtin_amdgcn_readfirstlane(v[2]);
        w[i+3] = __builtin_amdgcn_readfirstlane(v[3]);
    }

    float hA[6]={0,0,0,0,0,0}, cA[6]={0,0,0,0,0,0};
    float hB[6]={0,0,0,0,0,0}, cB[6]={0,0,0,0,0,0};

    const long long RSTR = (long long)NN*24;        // xp row stride in shorts
    const short* pA = xp + ((long long)(tsA - WARM)*NN + n)*24;  // may be <xp for b=0: al zeros
    const short* pB = xp + ((long long)(tsB - WARM)*NN + n)*24;

    uintx4 a0 = *(const uintx4*)(pA);
    uintx4 a1 = *(const uintx4*)(pA + 8);
    uintx4 a2 = *(const uintx4*)(pA + 16);
    uintx4 b0 = *(const uintx4*)(pB);
    uintx4 b1 = *(const uintx4*)(pB + 8);
    uintx4 b2 = *(const uintx4*)(pB + 16);

    for (int s = -WARM; s < CHUNK; ++s) {
        // issue next-row loads (depth-1: consumed next iteration, ~2800cy away)
        const short* qA = pA + RSTR;
        uintx4 nA0 = *(const uintx4*)(qA), nA1 = *(const uintx4*)(qA + 8), nA2 = *(const uintx4*)(qA + 16);
        const short* qB = pB + RSTR;
        uintx4 nB0 = *(const uintx4*)(qB), nB1 = *(const uintx4*)(qB + 8), nB2 = *(const uintx4*)(qB + 16);

        if (b == 0 && s == 0) {                     // chunk 0 starts from the true init
            #pragma unroll
            for (int j=0;j<6;++j){ hA[j]=0.f; cA[j]=0.f; }
        }

        unsigned xwA[12], xwB[12];
        #pragma unroll
        for (int k=0;k<4;++k){
            xwA[k]=a0[k]; xwA[4+k]=a1[k]; xwA[8+k]=a2[k];
            xwB[k]=b0[k]; xwB[4+k]=b1[k]; xwB[8+k]=b2[k];
        }

        float hnA[6], hnB[6];
        #pragma unroll
        for (int j=0;j<6;++j){                      // A/B interleave: B's fma fills A's trans latency
            jstep(w, xwA, j, hA, hnA, cA);
            jstep(w, xwB, j, hB, hnB, cB);
        }
        #pragma unroll
        for (int j=0;j<6;++j){ hA[j]=hnA[j]; hB[j]=hnB[j]; }

        if (s >= 0) {
            int baseA = (tsA + s)*6*128 + n;        // A[m=(t,j)][k=n], stride 128
            int baseB = (tsB + s)*6*128 + n;
            #pragma unroll
            for (int j=0;j<6;++j){
                al[baseA + j*128] = f2bf(hnA[j]);
                al[baseB + j*128] = f2bf(hnB[j]);
            }
        }
        a0=nA0; a1=nA1; a2=nA2; pA += RSTR;
        b0=nB0; b1=nB1; b2=nB2; pB += RSTR;
    }
}

// ---------------- pipelined conv as 3-tap (kh) GEMM, bf16 MFMA 16x16x32 ----------------
// Tile 192 rows x 112 cols, t-group aligned (192 = 32*6) so the +-1 kh halo never
// crosses a tile boundary (h=-1/6 rows are zero via vmask) -> A staging is exactly
// 768 chunks = 3 clean instructions/wave, no halo/tail/zero-page/bounds checks.
// A LDS layout is [row][q^swz] so consecutive chunks are 64B-contiguous per row:
// 16 rows x 64B = 16 cache-line requests per global_load_lds (was 64 with [q][row]).
// Double-buffered A (2x12.3KB) + B (2x21.5KB) = 67.6KB -> 2 blocks/CU; grids
// 1024/1024/512 blocks against 512 resident slots = exact 2/2/1 scheduling rounds.
template<int KP, int NTF, bool STATS>
__global__ __launch_bounds__(256) void conv_pipe(
    const short* __restrict__ In, const short* __restrict__ Wm,
    const float* __restrict__ bias, short* __restrict__ Out,
    float* __restrict__ stats)
{
    constexpr int KS = KP/32;
    constexpr int MR = 192;                         // rows per tile (32 t-groups)
    __shared__ alignas(16) short Abuf[2][MR*4*8];   // 12.3 KB per buffer
    __shared__ alignas(16) short Bbuf[2][1344*8];   // 21.5 KB per buffer
    __shared__ float sst[2][112];

    const int tid   = threadIdx.x;
    const int lane  = tid & 63;
    const int wv    = tid >> 6;
    const int l16   = lane & 15;
    const int q     = lane >> 4;
    const int m0    = blockIdx.x * MR;              // t-group aligned (192 % 6 == 0)
    const int nbase = blockIdx.y * 112;

    if (STATS && tid < 112){ sst[0][tid]=0.f; sst[1][tid]=0.f; }

    auto stageA = [&](int ks, int b) {
        const int k0 = ks*32;
        #pragma unroll
        for (int it=0; it<3; ++it) {                // 768 chunks exactly, all real
            int c  = it*256 + tid;
            int r  = c >> 2;
            int qg = (c & 3) ^ ((r >> 1) & 3);      // bank swizzle (matches read side)
            gload16(In + (size_t)(m0 + r)*KP + k0 + qg*8, &Abuf[b][c*8]);
        }
    };
    auto stageB = [&](int ks, int b) {
        #pragma unroll
        for (int it=0; it<5; ++it) {                // chunks 0..1279
            int c    = it*256 + tid;
            int run  = c / 112;
            int ridx = c - run*112;
            gload16(Wm + ((size_t)(ks*12 + run)*NTF + nbase + ridx)*8, &Bbuf[b][c*8]);
        }
        {                                           // tail 1280..1343, all 4 waves (dup ok)
            int c    = 1280 + (tid & 63);
            int run  = c / 112;
            int ridx = c - run*112;
            gload16(Wm + ((size_t)(ks*12 + run)*NTF + nbase + ridx)*8, &Bbuf[b][c*8]);
        }
    };

    // per-(mf,kh) A validity + swizzled LDS byte-chunk offsets (hoisted)
    bool vmask[3][3];
    int  aoff[3][3];
    #pragma unroll
    for (int mf=0; mf<3; ++mf){
        int mrow = wv*48 + mf*16 + l16;
        int m6 = mrow % 6;                          // m0 % 6 == 0
        #pragma unroll
        for (int kh=0; kh<3; ++kh){
            int hh = m6 + kh - 1;
            vmask[mf][kh] = (hh >= 0) && (hh < 6);
            int rr = mrow + kh - 1;
            rr = rr < 0 ? 0 : (rr > MR-1 ? MR-1 : rr);  // clamp (value discarded via vmask)
            aoff[mf][kh] = (rr*4 + (q ^ ((rr >> 1) & 3)))*8;
        }
    }

    floatx4 acc[3][7];
    #pragma unroll
    for (int a=0;a<3;++a)
      #pragma unroll
      for (int b=0;b<7;++b)
        #pragma unroll
        for (int r=0;r<4;++r) acc[a][b][r] = 0.f;

    stageA(0, 0); stageB(0, 0);                     // 9 VMEM issues per wave

    for (int ks = 0; ks < KS; ++ks) {
        const int cur = ks & 1;
        if (ks + 1 < KS) {
            stageA(ks+1, cur^1); stageB(ks+1, cur^1);          // 9 more in flight
            asm volatile("s_waitcnt vmcnt(9)" ::: "memory");   // cur's 9 done
        } else {
            asm volatile("s_waitcnt vmcnt(0)" ::: "memory");
        }
        asm volatile("s_barrier" ::: "memory");     // cur buffer ready for all waves

        #pragma unroll
        for (int kh = 0; kh < 3; ++kh) {
            bf16x8 z = {0,0,0,0,0,0,0,0};
            bf16x8 af[3];
            #pragma unroll
            for (int mf=0; mf<3; ++mf){
                bf16x8 a = *(const bf16x8*)(&Abuf[cur][aoff[mf][kh]]);
                af[mf] = vmask[mf][kh] ? a : z;
            }
            const int bbase = (kh*4 + q)*112 + l16;
            #pragma unroll
            for (int nf = 0; nf < 7; ++nf) {
                bf16x8 b = *(const bf16x8*)(&Bbuf[cur][(bbase + nf*16)*8]);
                #pragma unroll
                for (int mf=0; mf<3; ++mf)
                    acc[mf][nf] = __builtin_amdgcn_mfma_f32_16x16x32_bf16(af[mf], b, acc[mf][nf], 0, 0, 0);
            }
        }
        asm volatile("s_barrier" ::: "memory");     // all reads of cur done (WAR for ks+2 staging)
    }

    // epilogue: bias + relu + store bf16 (+ BN partial stats for conv3)
    #pragma unroll
    for (int nf = 0; nf < 7; ++nf) {
        const int col = nbase + nf*16 + l16;
        const float bv = bias[col];
        float s1 = 0.f, s2 = 0.f;
        #pragma unroll
        for (int mf = 0; mf < 3; ++mf) {
            floatx4 v = acc[mf][nf];
            #pragma unroll
            for (int r = 0; r < 4; ++r) {
                float y = fmaxf(v[r] + bv, 0.f);
                const int mg = m0 + wv*48 + mf*16 + q*4 + r; // C/D: row=q*4+r, col=l16
                Out[(size_t)mg*NTF + col] = f2bf(y);
                if (STATS){ s1 += y; s2 += y*y; }
            }
        }
        if (STATS) {
            s1 += __shfl_xor(s1, 16); s1 += __shfl_xor(s1, 32);
            s2 += __shfl_xor(s2, 16); s2 += __shfl_xor(s2, 32);
            if (q == 0 && col < 97) {
                atomicAdd(&sst[0][col], s1);
                atomicAdd(&sst[1][col], s2);
            }
        }
    }
    if (STATS) {
        __syncthreads();
        if (tid < 97) {
            atomicAdd(&stats[tid],     sst[0][tid]);
            atomicAdd(&stats[128+tid], sst[1][tid]);
        }
    }
}

// ---------------- BN (batch stats) + affine + Linear(6,6) + layout transpose ----------------
__global__ __launch_bounds__(256) void final_kernel(
    const short* __restrict__ f3, const float* __restrict__ stats,
    const float* __restrict__ gamma, const float* __restrict__ beta,
    const float* __restrict__ Wl, const float* __restrict__ bl,
    float* __restrict__ out)
{
    const int idx = blockIdx.x*256 + threadIdx.x;  // t*97+n
    const int t = idx / NN;
    const int n = idx - t*NN;
    const float inv_cnt = 1.0f / (float)M_TOT;
    const float mean = stats[n] * inv_cnt;
    const float var  = stats[128+n] * inv_cnt - mean*mean;
    const float rstd = rsqrtf(var + 1e-5f);
    const float ga = gamma[n], be = beta[n];
    float v[6];
    #pragma unroll
    for (int hh=0; hh<6; ++hh) {
        float raw = bf2f(f3[(size_t)(t*6 + hh)*112 + n]);
        v[hh] = (raw - mean)*rstd*ga + be;
    }
    #pragma unroll
    for (int ho=0; ho<6; ++ho) {
        float o = bl[ho];
        #pragma unroll
        for (int hh=0; hh<6; ++hh) o = fmaf(v[hh], Wl[ho*6+hh], o);
        out[(size_t)idx*6 + ho] = o;
    }
}

extern "C" void kernel_launch(void* const* d_in, const int* in_sizes, int n_in,
                              void* d_out, int out_size, void* d_ws, size_t ws_size,
                              hipStream_t stream)
{
    const float* X    = (const float*)d_in[1];
    const float* Wih  = (const float*)d_in[3];
    const float* Whh  = (const float*)d_in[4];
    const float* bih  = (const float*)d_in[5];
    const float* bhh  = (const float*)d_in[6];
    const float* Wc1  = (const float*)d_in[7];
    const float* bc1  = (const float*)d_in[8];
    const float* Wc2  = (const float*)d_in[9];
    const float* bc2  = (const float*)d_in[10];
    const float* Wc3  = (const float*)d_in[11];
    const float* bc3  = (const float*)d_in[12];
    const float* gam  = (const float*)d_in[13];
    const float* bet  = (const float*)d_in[14];
    const float* Wl   = (const float*)d_in[15];
    const float* bl   = (const float*)d_in[16];

    char* ws = (char*)d_ws;
    short* al = (short*)(ws + AL_OFF);
    short* f1 = (short*)(ws + F1_OFF);
    short* f2 = (short*)(ws + F2_OFF);
    short* f3 = (short*)(ws + F3_OFF);
    short* xp = (short*)(ws + XP_OFF);   // aliases f1/f2 (dead before conv1)
    short* w1 = (short*)(ws + W1_OFF);
    short* w2 = (short*)(ws + W2_OFF);
    short* w3 = (short*)(ws + W3_OFF);
    float* b1 = (float*)(ws + B1_OFF);
    float* b2 = (float*)(ws + B2_OFF);
    float* b3 = (float*)(ws + B3_OFF);
    float* st = (float*)(ws + ST_OFF);
    unsigned* wh = (unsigned*)(ws + WH_OFF);

    hipMemsetAsync(al, 0, AL_SZ, stream);       // zero-pad columns 97..127 of al (also the
                                                // zero source for block-0 warm reads)
    hipMemsetAsync(st, 0, 1024, stream);        // BN stat accumulators

    repack_all<<<(RT4+255)/256, 256, 0, stream>>>(Wc1, bc1, w1, b1,
                                                  Wc2, bc2, w2, b2,
                                                  Wc3, bc3, w3, b3,
                                                  Whh, wh);

    xproj_kernel<<<(T_STEPS*NN)/256, 256, 0, stream>>>(X, Wih, bih, bhh, xp);

    lstm_kernel<<<NCHUNK/2, 128, 0, stream>>>(xp, wh, al);

    conv_pipe<128,224,false><<<dim3(M_TOT/192, 2), 256, 0, stream>>>(al, w1, b1, f1, nullptr);
    conv_pipe<224,224,false><<<dim3(M_TOT/192, 2), 256, 0, stream>>>(f1, w2, b2, f2, nullptr);
    conv_pipe<224,112,true ><<<dim3(M_TOT/192, 1), 256, 0, stream>>>(f2, w3, b3, f3, st);

    final_kernel<<<(T_STEPS*NN)/256, 256, 0, stream>>>(f3, st, gam, bet, Wl, bl, (float*)d_out);
}

// Round 7
// 332.329 us; speedup vs baseline: 1.1207x; 1.1207x over previous
//
#include <hip/hip_runtime.h>

#define DI __device__ __forceinline__

using floatx4 = __attribute__((ext_vector_type(4))) float;
using bf16x8  = __attribute__((ext_vector_type(8))) short;
using bf16x4  = __attribute__((ext_vector_type(4))) short;
using uintx4  = __attribute__((ext_vector_type(4))) unsigned int;

constexpr int T_STEPS = 16384;
constexpr int NN      = 97;
constexpr int M_TOT   = T_STEPS * 6;   // 98304 rows of the (t,h) x channel matrices
constexpr int CHUNK   = 16;            // stored steps per chunk
constexpr int WARM    = 12;            // warm-up steps
constexpr int NCHUNK  = T_STEPS / CHUNK;   // 1024

// ---------------- ws layout (bytes, all 256B aligned) ----------------
constexpr size_t AL_OFF = 0;                  constexpr size_t AL_SZ = (size_t)M_TOT*128*2; // al: [M][128] bf16 (97 used, zero-pad)
constexpr size_t F1_OFF = AL_OFF + AL_SZ;     constexpr size_t F1_SZ = (size_t)M_TOT*224*2; // f1: [M][224] bf16 (194 used)
constexpr size_t F2_OFF = F1_OFF + F1_SZ;     constexpr size_t F2_SZ = F1_SZ;
constexpr size_t F3_OFF = F2_OFF + F2_SZ;     constexpr size_t F3_SZ = (size_t)M_TOT*112*2; // f3: [M][112] bf16 (97 used)
constexpr size_t W1_OFF = F3_OFF + F3_SZ;     constexpr size_t W1_SZ = (size_t)3*224*128*2;
constexpr size_t W2_OFF = W1_OFF + W1_SZ;     constexpr size_t W2_SZ = (size_t)3*224*224*2;
constexpr size_t W3_OFF = W2_OFF + W2_SZ;     constexpr size_t W3_SZ = (size_t)3*112*224*2;
constexpr size_t B1_OFF = W3_OFF + W3_SZ;
constexpr size_t B2_OFF = B1_OFF + 1024;
constexpr size_t B3_OFF = B2_OFF + 1024;
constexpr size_t ST_OFF = B3_OFF + 1024;      // stats: [0..96]=sum, [128..224]=sumsq
constexpr size_t WH_OFF = ST_OFF + 1024;      // packed f16 Whh: 72 u32 (288 B)
// xp (f16 [T][97][24] = 76.3 MB) aliased onto f1+f2 (177 MB): dead before conv1 writes f1.
// Reads 1 row past T (prefetch) and up to 12 rows before 0 (ch==0 warm; lands in the
// al region -- values are garbage-but-in-bounds, discarded by the s==0 state reset).
constexpr size_t XP_OFF = F1_OFF;

DI short f2bf(float f){
    union { float f; unsigned u; } a; a.f = f;
    unsigned r = (a.u + 0x7FFFu + ((a.u >> 16) & 1u)) >> 16;
    return (short)r;
}
DI float bf2f(short s){
    union { unsigned u; float f; } a; a.u = ((unsigned)(unsigned short)s) << 16;
    return a.f;
}
DI short f2h(float f){
    _Float16 h = (_Float16)f;
    return __builtin_bit_cast(short, h);
}
DI float h2f_lo(unsigned u){
    _Float16 x = __builtin_bit_cast(_Float16, (unsigned short)(u & 0xffffu));
    return (float)x;
}
DI float h2f_hi(unsigned u){
    _Float16 x = __builtin_bit_cast(_Float16, (unsigned short)(u >> 16));
    return (float)x;
}
DI float fsig(float x){
    float e = __builtin_amdgcn_exp2f(x * -1.442695041f);
    return __builtin_amdgcn_rcpf(1.0f + e);
}
DI float ftanh(float x){
    float e = __builtin_amdgcn_exp2f(x * 2.885390082f);   // exp(2x)
    return 1.0f - 2.0f * __builtin_amdgcn_rcpf(e + 1.0f); // graceful at +-inf
}

// acc += f16(lo half of SGPR w) * h   -- weight stays in an SGPR, zero VGPR cost
DI float mixlo(unsigned w, float h, float acc){
    asm("v_fma_mix_f32 %0, %1, %2, %0 op_sel:[0,0,0] op_sel_hi:[1,0,0]"
        : "+v"(acc) : "s"(w), "v"(h));
    return acc;
}
// acc += f16(hi half of SGPR w) * h
DI float mixhi(unsigned w, float h, float acc){
    asm("v_fma_mix_f32 %0, %1, %2, %0 op_sel:[1,0,0] op_sel_hi:[1,0,0]"
        : "+v"(acc) : "s"(w), "v"(h));
    return acc;
}

// async global->LDS, 16B per lane; LDS dest must be wave-uniform base + lane*16
DI void gload16(const void* g, void* l) {
    __builtin_amdgcn_global_load_lds(
        (const __attribute__((address_space(1))) unsigned int*)g,
        (__attribute__((address_space(3))) unsigned int*)l, 16, 0, 0);
}

// ---------------- weight repack (convs + packed-f16 Whh in one dispatch) ----------------
// conv layout: Wg[ks][kh][q][n][j]: k = ks*32 + q*8 + j (zero-padded), value = Wc[n][k][kh][kw=1]
DI void repack_one(const float* Wc, const float* bc, short* wdst, float* bdst,
                   int COUT, int CIN, int NT, int i)
{
    int j  = i & 7;
    int t1 = i >> 3;
    int n  = t1 % NT;
    int t2 = t1 / NT;
    int qq = t2 & 3;
    int t3 = t2 >> 2;
    int kh = t3 % 3;
    int ks = t3 / 3;
    int k  = ks*32 + qq*8 + j;
    float v = 0.f;
    if (n < COUT && k < CIN) v = Wc[((n*CIN + k)*3 + kh)*3 + 1]; // kw=1 only (W=1, pad=1)
    wdst[i] = f2bf(v);
    if (i < NT) bdst[i] = (i < COUT) ? bc[i] : 0.f;
}

constexpr int RT1 = 3*224*128;
constexpr int RT2 = RT1 + 3*224*224;
constexpr int RT3 = RT2 + 3*112*224;
constexpr int RT4 = RT3 + 72;          // 72 packed Whh words

__global__ __launch_bounds__(256) void repack_all(
    const float* __restrict__ Wc1, const float* __restrict__ bc1, short* __restrict__ w1, float* __restrict__ b1,
    const float* __restrict__ Wc2, const float* __restrict__ bc2, short* __restrict__ w2, float* __restrict__ b2,
    const float* __restrict__ Wc3, const float* __restrict__ bc3, short* __restrict__ w3, float* __restrict__ b3,
    const float* __restrict__ Whh, unsigned* __restrict__ wh)
{
    int idx = blockIdx.x*256 + threadIdx.x;
    if (idx < RT1)       repack_one(Wc1, bc1, w1, b1, 194,  97, 224, idx);
    else if (idx < RT2)  repack_one(Wc2, bc2, w2, b2, 194, 194, 224, idx - RT1);
    else if (idx < RT3)  repack_one(Wc3, bc3, w3, b3,  97, 194, 112, idx - RT2);
    else if (idx < RT4) {
        int i = idx - RT3;             // 0..71: g = gate row (0..23), dp = d-pair (0..2)
        int g = i / 3, dp = i - g*3;
        unsigned lo = (unsigned short)f2h(Whh[g*6 + 2*dp]);
        unsigned hi = (unsigned short)f2h(Whh[g*6 + 2*dp + 1]);
        wh[i] = lo | (hi << 16);
    }
}

// ---------------- x-projection: f16, plain gate order, LDS-staged coalesced stores ----
__global__ __launch_bounds__(256) void xproj_kernel(
    const float* __restrict__ X, const float* __restrict__ Wih,
    const float* __restrict__ bih, const float* __restrict__ bhh,
    short* __restrict__ xp)
{
    __shared__ alignas(16) short sbuf[256*24];      // 12 KB
    const int tid = threadIdx.x;
    const int idx = blockIdx.x*256 + tid;           // t*97+n, exactly T*97 threads
    const floatx4* xv = (const floatx4*)(X + (size_t)idx*12);
    floatx4 x0 = xv[0], x1 = xv[1], x2 = xv[2];
    float xr[12];
    #pragma unroll
    for (int f=0; f<4; ++f){ xr[f]=x0[f]; xr[4+f]=x1[f]; xr[8+f]=x2[f]; }

    short o24[24];
    #pragma unroll
    for (int g=0; g<24; ++g) {
        float s = bih[g] + bhh[g];
        #pragma unroll
        for (int f=0; f<12; ++f) s = fmaf(xr[f], Wih[g*12+f], s);
        o24[g] = f2h(s);                            // plain order: row g = Whh/bias row g
    }
    #pragma unroll
    for (int k=0; k<3; ++k)
        *(uintx4*)(&sbuf[tid*24 + k*8]) = *(const uintx4*)(&o24[k*8]);
    __syncthreads();
    const size_t base = (size_t)blockIdx.x * (256*24);
    #pragma unroll
    for (int k=0; k<3; ++k) {
        int off = k*2048 + tid*8;                   // shorts; 16B per lane, contiguous
        *(uintx4*)(xp + base + off) = *(const uintx4*)(&sbuf[off]);
    }
}

// ---------------- LSTM: 1 lane = 1 full chain, chain-major packing, SGPR f16 weights ----
// Rounds 3-6 proved: plain prefetch loads in the serial t-loop ALWAYS get sunk to
// their use (VGPR stuck at 36-64), exposing full memory latency per step. This
// version makes sinking impossible:
//   loads at loop top -> sched_barrier(0) (loads cannot move below)
//   -> full gate compute (~1000cy) -> asm "+v" pins on the loaded regs (first use;
//   the single s_waitcnt lands HERE, after the compute) -> rotate.
// Packing: chain id c = ch*97+n consecutive across lanes -> all 64 lanes active,
// xp reads contiguous (48B/lane, ~3KB/wave), grid = 388 blocks x 4 waves = 1552
// waves ~= 1.5/SIMD. Weights wave-uniform in 72 SGPRs (f16 pairs) via fma_mix.
// ch==0 lanes warm-read t<0 (in-bounds al region, garbage) -- discarded by the
// s==0 hard reset of h/c on those lanes.
__global__ __launch_bounds__(256, 1) void lstm_kernel(
    const short* __restrict__ xp, const unsigned* __restrict__ wpk,
    short* __restrict__ al)
{
    const int c  = blockIdx.x*256 + threadIdx.x;    // chain id, 0..99327
    const int ch = c / NN;
    const int n  = c - ch*NN;
    const int ts = ch*CHUNK;
    const bool ch0 = (ch == 0);

    unsigned w[72];                                 // packed f16 pairs, wave-uniform -> SGPRs
    #pragma unroll
    for (int i=0; i<72; i+=4){
        uintx4 v = *(const uintx4*)(wpk + i);
        w[i+0] = __builtin_amdgcn_readfirstlane(v[0]);
        w[i+1] = __builtin_amdgcn_readfirstlane(v[1]);
        w[i+2] = __builtin_amdgcn_readfirstlane(v[2]);
        w[i+3] = __builtin_amdgcn_readfirstlane(v[3]);
    }

    float h[6]  = {0,0,0,0,0,0};
    float cs[6] = {0,0,0,0,0,0};

    const long long RSTR = (long long)NN*24;        // xp row stride in shorts (4656 B)
    const short* p = xp + ((long long)(ts - WARM)*NN + n)*24;

    unsigned cur[12], nxt[12];
    {
        uintx4 t0 = *(const uintx4*)(p);
        uintx4 t1 = *(const uintx4*)(p + 8);
        uintx4 t2 = *(const uintx4*)(p + 16);
        #pragma unroll
        for (int k=0;k<4;++k){ cur[k]=t0[k]; cur[4+k]=t1[k]; cur[8+k]=t2[k]; }
    }

    for (int s = -WARM; s < CHUNK; ++s) {
        {   // issue next-row loads; sched_barrier keeps them issued here (not sunk)
            const short* q = p + RSTR;
            uintx4 t0 = *(const uintx4*)(q);
            uintx4 t1 = *(const uintx4*)(q + 8);
            uintx4 t2 = *(const uintx4*)(q + 16);
            #pragma unroll
            for (int k=0;k<4;++k){ nxt[k]=t0[k]; nxt[4+k]=t1[k]; nxt[8+k]=t2[k]; }
        }
        __builtin_amdgcn_sched_barrier(0);

        if (s == 0) {                               // chunk 0 starts from the true init
            #pragma unroll
            for (int j=0;j<6;++j){ h[j] = ch0 ? 0.f : h[j]; cs[j] = ch0 ? 0.f : cs[j]; }
        }

        float hn[6];
        #pragma unroll
        for (int j=0;j<6;++j){
            float gi = (j&1) ? h2f_hi(cur[(j)>>1])    : h2f_lo(cur[(j)>>1]);
            float gf = (j&1) ? h2f_hi(cur[(6+j)>>1])  : h2f_lo(cur[(6+j)>>1]);
            float gc = (j&1) ? h2f_hi(cur[(12+j)>>1]) : h2f_lo(cur[(12+j)>>1]);
            float go = (j&1) ? h2f_hi(cur[(18+j)>>1]) : h2f_lo(cur[(18+j)>>1]);
            #pragma unroll
            for (int dp=0; dp<3; ++dp){
                gi = mixlo(w[(j   )*3+dp], h[2*dp], gi); gi = mixhi(w[(j   )*3+dp], h[2*dp+1], gi);
                gf = mixlo(w[(6+j )*3+dp], h[2*dp], gf); gf = mixhi(w[(6+j )*3+dp], h[2*dp+1], gf);
                gc = mixlo(w[(12+j)*3+dp], h[2*dp], gc); gc = mixhi(w[(12+j)*3+dp], h[2*dp+1], gc);
                go = mixlo(w[(18+j)*3+dp], h[2*dp], go); go = mixhi(w[(18+j)*3+dp], h[2*dp+1], go);
            }
            float ig = fsig(gi), fg = fsig(gf), cg = ftanh(gc), og = fsig(go);
            cs[j] = fmaf(fg, cs[j], ig*cg);
            hn[j] = ftanh(og * ftanh(cs[j]));        // extra tanh, fed back (matches ref)
        }
        #pragma unroll
        for (int j=0;j<6;++j) h[j] = hn[j];

        if (s >= 0) {
            int base = (ts + s)*6*128 + n;           // A[m=(t,j)][k=n], stride 128
            #pragma unroll
            for (int j=0;j<6;++j) al[base + j*128] = f2bf(hn[j]);
        }

        // pin the prefetched regs HERE (first use -> the waitcnt lands after the
        // compute above; opaque asm cannot be sunk/remat'd), then rotate.
        #pragma unroll
        for (int k=0;k<12;++k){
            asm volatile("" : "+v"(nxt[k]));
            cur[k] = nxt[k];
        }
        p += RSTR;
    }
}

// ---------------- pipelined conv as 3-tap (kh) GEMM, bf16 MFMA 16x16x32 ----------------
// Tile 192 rows x 112 cols, t-group aligned (192 = 32*6) so the +-1 kh halo never
// crosses a tile boundary (h=-1/6 rows are zero via vmask) -> A staging is exactly
// 768 chunks = 3 clean instructions/wave, no halo/tail/zero-page/bounds checks.
// A LDS layout is [row][q^swz] so consecutive chunks are 64B-contiguous per row:
// 16 rows x 64B = 16 cache-line requests per global_load_lds (was 64 with [q][row]).
// Double-buffered A (2x12.3KB) + B (2x21.5KB) = 67.6KB -> 2 blocks/CU; grids
// 1024/1024/512 blocks against 512 resident slots = exact 2/2/1 scheduling rounds.
template<int KP, int NTF, bool STATS>
__global__ __launch_bounds__(256) void conv_pipe(
    const short* __restrict__ In, const short* __restrict__ Wm,
    const float* __restrict__ bias, short* __restrict__ Out,
    float* __restrict__ stats)
{
    constexpr int KS = KP/32;
    constexpr int MR = 192;                         // rows per tile (32 t-groups)
    __shared__ alignas(16) short Abuf[2][MR*4*8];   // 12.3 KB per buffer
    __shared__ alignas(16) short Bbuf[2][1344*8];   // 21.5 KB per buffer
    __shared__ float sst[2][112];

    const int tid   = threadIdx.x;
    const int lane  = tid & 63;
    const int wv    = tid >> 6;
    const int l16   = lane & 15;
    const int q     = lane >> 4;
    const int m0    = blockIdx.x * MR;              // t-group aligned (192 % 6 == 0)
    const int nbase = blockIdx.y * 112;

    if (STATS && tid < 112){ sst[0][tid]=0.f; sst[1][tid]=0.f; }

    auto stageA = [&](int ks, int b) {
        const int k0 = ks*32;
        #pragma unroll
        for (int it=0; it<3; ++it) {                // 768 chunks exactly, all real
            int c  = it*256 + tid;
            int r  = c >> 2;
            int qg = (c & 3) ^ ((r >> 1) & 3);      // bank swizzle (matches read side)
            gload16(In + (size_t)(m0 + r)*KP + k0 + qg*8, &Abuf[b][c*8]);
        }
    };
    auto stageB = [&](int ks, int b) {
        #pragma unroll
        for (int it=0; it<5; ++it) {                // chunks 0..1279
            int c    = it*256 + tid;
            int run  = c / 112;
            int ridx = c - run*112;
            gload16(Wm + ((size_t)(ks*12 + run)*NTF + nbase + ridx)*8, &Bbuf[b][c*8]);
        }
        {                                           // tail 1280..1343, all 4 waves (dup ok)
            int c    = 1280 + (tid & 63);
            int run  = c / 112;
            int ridx = c - run*112;
            gload16(Wm + ((size_t)(ks*12 + run)*NTF + nbase + ridx)*8, &Bbuf[b][c*8]);
        }
    };

    // per-(mf,kh) A validity + swizzled LDS byte-chunk offsets (hoisted)
    bool vmask[3][3];
    int  aoff[3][3];
    #pragma unroll
    for (int mf=0; mf<3; ++mf){
        int mrow = wv*48 + mf*16 + l16;
        int m6 = mrow % 6;                          // m0 % 6 == 0
        #pragma unroll
        for (int kh=0; kh<3; ++kh){
            int hh = m6 + kh - 1;
            vmask[mf][kh] = (hh >= 0) && (hh < 6);
            int rr = mrow + kh - 1;
            rr = rr < 0 ? 0 : (rr > MR-1 ? MR-1 : rr);  // clamp (value discarded via vmask)
            aoff[mf][kh] = (rr*4 + (q ^ ((rr >> 1) & 3)))*8;
        }
    }

    floatx4 acc[3][7];
    #pragma unroll
    for (int a=0;a<3;++a)
      #pragma unroll
      for (int b=0;b<7;++b)
        #pragma unroll
        for (int r=0;r<4;++r) acc[a][b][r] = 0.f;

    stageA(0, 0); stageB(0, 0);                     // 9 VMEM issues per wave

    for (int ks = 0; ks < KS; ++ks) {
        const int cur = ks & 1;
        if (ks + 1 < KS) {
            stageA(ks+1, cur^1); stageB(ks+1, cur^1);          // 9 more in flight
            asm volatile("s_waitcnt vmcnt(9)" ::: "memory");   // cur's 9 done
        } else {
            asm volatile("s_waitcnt vmcnt(0)" ::: "memory");
        }
        asm volatile("s_barrier" ::: "memory");     // cur buffer ready for all waves

        #pragma unroll
        for (int kh = 0; kh < 3; ++kh) {
            bf16x8 z = {0,0,0,0,0,0,0,0};
            bf16x8 af[3];
            #pragma unroll
            for (int mf=0; mf<3; ++mf){
                bf16x8 a = *(const bf16x8*)(&Abuf[cur][aoff[mf][kh]]);
                af[mf] = vmask[mf][kh] ? a : z;
            }
            const int bbase = (kh*4 + q)*112 + l16;
            #pragma unroll
            for (int nf = 0; nf < 7; ++nf) {
                bf16x8 b = *(const bf16x8*)(&Bbuf[cur][(bbase + nf*16)*8]);
                #pragma unroll
                for (int mf=0; mf<3; ++mf)
                    acc[mf][nf] = __builtin_amdgcn_mfma_f32_16x16x32_bf16(af[mf], b, acc[mf][nf], 0, 0, 0);
            }
        }
        asm volatile("s_barrier" ::: "memory");     // all reads of cur done (WAR for ks+2 staging)
    }

    // epilogue: bias + relu + store bf16 (+ BN partial stats for conv3)
    #pragma unroll
    for (int nf = 0; nf < 7; ++nf) {
        const int col = nbase + nf*16 + l16;
        const float bv = bias[col];
        float s1 = 0.f, s2 = 0.f;
        #pragma unroll
        for (int mf = 0; mf < 3; ++mf) {
            floatx4 v = acc[mf][nf];
            #pragma unroll
            for (int r = 0; r < 4; ++r) {
                float y = fmaxf(v[r] + bv, 0.f);
                const int mg = m0 + wv*48 + mf*16 + q*4 + r; // C/D: row=q*4+r, col=l16
                Out[(size_t)mg*NTF + col] = f2bf(y);
                if (STATS){ s1 += y; s2 += y*y; }
            }
        }
        if (STATS) {
            s1 += __shfl_xor(s1, 16); s1 += __shfl_xor(s1, 32);
            s2 += __shfl_xor(s2, 16); s2 += __shfl_xor(s2, 32);
            if (q == 0 && col < 97) {
                atomicAdd(&sst[0][col], s1);
                atomicAdd(&sst[1][col], s2);
            }
        }
    }
    if (STATS) {
        __syncthreads();
        if (tid < 97) {
            atomicAdd(&stats[tid],     sst[0][tid]);
            atomicAdd(&stats[128+tid], sst[1][tid]);
        }
    }
}

// ---------------- BN (batch stats) + affine + Linear(6,6) + layout transpose ----------------
__global__ __launch_bounds__(256) void final_kernel(
    const short* __restrict__ f3, const float* __restrict__ stats,
    const float* __restrict__ gamma, const float* __restrict__ beta,
    const float* __restrict__ Wl, const float* __restrict__ bl,
    float* __restrict__ out)
{
    const int idx = blockIdx.x*256 + threadIdx.x;  // t*97+n
    const int t = idx / NN;
    const int n = idx - t*NN;
    const float inv_cnt = 1.0f / (float)M_TOT;
    const float mean = stats[n] * inv_cnt;
    const float var  = stats[128+n] * inv_cnt - mean*mean;
    const float rstd = rsqrtf(var + 1e-5f);
    const float ga = gamma[n], be = beta[n];
    float v[6];
    #pragma unroll
    for (int hh=0; hh<6; ++hh) {
        float raw = bf2f(f3[(size_t)(t*6 + hh)*112 + n]);
        v[hh] = (raw - mean)*rstd*ga + be;
    }
    #pragma unroll
    for (int ho=0; ho<6; ++ho) {
        float o = bl[ho];
        #pragma unroll
        for (int hh=0; hh<6; ++hh) o = fmaf(v[hh], Wl[ho*6+hh], o);
        out[(size_t)idx*6 + ho] = o;
    }
}

extern "C" void kernel_launch(void* const* d_in, const int* in_sizes, int n_in,
                              void* d_out, int out_size, void* d_ws, size_t ws_size,
                              hipStream_t stream)
{
    const float* X    = (const float*)d_in[1];
    const float* Wih  = (const float*)d_in[3];
    const float* Whh  = (const float*)d_in[4];
    const float* bih  = (const float*)d_in[5];
    const float* bhh  = (const float*)d_in[6];
    const float* Wc1  = (const float*)d_in[7];
    const float* bc1  = (const float*)d_in[8];
    const float* Wc2  = (const float*)d_in[9];
    const float* bc2  = (const float*)d_in[10];
    const float* Wc3  = (const float*)d_in[11];
    const float* bc3  = (const float*)d_in[12];
    const float* gam  = (const float*)d_in[13];
    const float* bet  = (const float*)d_in[14];
    const float* Wl   = (const float*)d_in[15];
    const float* bl   = (const float*)d_in[16];

    char* ws = (char*)d_ws;
    short* al = (short*)(ws + AL_OFF);
    short* f1 = (short*)(ws + F1_OFF);
    short* f2 = (short*)(ws + F2_OFF);
    short* f3 = (short*)(ws + F3_OFF);
    short* xp = (short*)(ws + XP_OFF);   // aliases f1/f2 (dead before conv1)
    short* w1 = (short*)(ws + W1_OFF);
    short* w2 = (short*)(ws + W2_OFF);
    short* w3 = (short*)(ws + W3_OFF);
    float* b1 = (float*)(ws + B1_OFF);
    float* b2 = (float*)(ws + B2_OFF);
    float* b3 = (float*)(ws + B3_OFF);
    float* st = (float*)(ws + ST_OFF);
    unsigned* wh = (unsigned*)(ws + WH_OFF);

    hipMemsetAsync(al, 0, AL_SZ, stream);       // zero-pad columns 97..127 of al (also the
                                                // in-bounds target of ch==0 warm reads)
    hipMemsetAsync(st, 0, 1024, stream);        // BN stat accumulators

    repack_all<<<(RT4+255)/256, 256, 0, stream>>>(Wc1, bc1, w1, b1,
                                                  Wc2, bc2, w2, b2,
                                                  Wc3, bc3, w3, b3,
                                                  Whh, wh);

    xproj_kernel<<<(T_STEPS*NN)/256, 256, 0, stream>>>(X, Wih, bih, bhh, xp);

    lstm_kernel<<<(NCHUNK*NN)/256, 256, 0, stream>>>(xp, wh, al);

    conv_pipe<128,224,false><<<dim3(M_TOT/192, 2), 256, 0, stream>>>(al, w1, b1, f1, nullptr);
    conv_pipe<224,224,false><<<dim3(M_TOT/192, 2), 256, 0, stream>>>(f1, w2, b2, f2, nullptr);
    conv_pipe<224,112,true ><<<dim3(M_TOT/192, 1), 256, 0, stream>>>(f2, w3, b3, f3, st);

    final_kernel<<<(T_STEPS*NN)/256, 256, 0, stream>>>(f3, st, gam, bet, Wl, bl, (float*)d_out);
}

// Round 8
// 330.271 us; speedup vs baseline: 1.1277x; 1.0062x over previous
//
#include <hip/hip_runtime.h>

#define DI __device__ __forceinline__

using floatx4 = __attribute__((ext_vector_type(4))) float;
using bf16x8  = __attribute__((ext_vector_type(8))) short;
using bf16x4  = __attribute__((ext_vector_type(4))) short;
using uintx4  = __attribute__((ext_vector_type(4))) unsigned int;

constexpr int T_STEPS = 16384;
constexpr int NN      = 97;
constexpr int M_TOT   = T_STEPS * 6;   // 98304 rows of the (t,h) x channel matrices
constexpr int CHUNK   = 16;            // stored steps per chunk
constexpr int WARM    = 12;            // warm-up steps  (WARM+CHUNK even -> clean 2x unroll)
constexpr int NCHUNK  = T_STEPS / CHUNK;   // 1024

// ---------------- ws layout (bytes, all 256B aligned) ----------------
constexpr size_t AL_OFF = 0;                  constexpr size_t AL_SZ = (size_t)M_TOT*128*2; // al: [M][128] bf16 (97 used, zero-pad)
constexpr size_t F1_OFF = AL_OFF + AL_SZ;     constexpr size_t F1_SZ = (size_t)M_TOT*224*2; // f1: [M][224] bf16 (194 used)
constexpr size_t F2_OFF = F1_OFF + F1_SZ;     constexpr size_t F2_SZ = F1_SZ;
constexpr size_t F3_OFF = F2_OFF + F2_SZ;     constexpr size_t F3_SZ = (size_t)M_TOT*112*2; // f3: [M][112] bf16 (97 used)
constexpr size_t W1_OFF = F3_OFF + F3_SZ;     constexpr size_t W1_SZ = (size_t)3*224*128*2;
constexpr size_t W2_OFF = W1_OFF + W1_SZ;     constexpr size_t W2_SZ = (size_t)3*224*224*2;
constexpr size_t W3_OFF = W2_OFF + W2_SZ;     constexpr size_t W3_SZ = (size_t)3*112*224*2;
constexpr size_t B1_OFF = W3_OFF + W3_SZ;
constexpr size_t B2_OFF = B1_OFF + 1024;
constexpr size_t B3_OFF = B2_OFF + 1024;
constexpr size_t ST_OFF = B3_OFF + 1024;      // stats: [0..96]=sum, [128..224]=sumsq
constexpr size_t WH_OFF = ST_OFF + 1024;      // packed f16 Whh: 72 u32 (288 B)
// xp (f16 [T][97][24] = 76.3 MB) aliased onto f1+f2 (177 MB): dead before conv1 writes f1.
// Reads 1 row past T (prefetch) and up to 12 rows before 0 (ch==0 warm; lands in the
// zeroed al region -- in-bounds, values discarded by the s==0 state reset).
constexpr size_t XP_OFF = F1_OFF;

DI short f2bf(float f){
    union { float f; unsigned u; } a; a.f = f;
    unsigned r = (a.u + 0x7FFFu + ((a.u >> 16) & 1u)) >> 16;
    return (short)r;
}
DI float bf2f(short s){
    union { unsigned u; float f; } a; a.u = ((unsigned)(unsigned short)s) << 16;
    return a.f;
}
DI short f2h(float f){
    _Float16 h = (_Float16)f;
    return __builtin_bit_cast(short, h);
}
DI float h2f_lo(unsigned u){
    _Float16 x = __builtin_bit_cast(_Float16, (unsigned short)(u & 0xffffu));
    return (float)x;
}
DI float h2f_hi(unsigned u){
    _Float16 x = __builtin_bit_cast(_Float16, (unsigned short)(u >> 16));
    return (float)x;
}
DI float fsig(float x){
    float e = __builtin_amdgcn_exp2f(x * -1.442695041f);
    return __builtin_amdgcn_rcpf(1.0f + e);
}
DI float ftanh(float x){
    float e = __builtin_amdgcn_exp2f(x * 2.885390082f);   // exp(2x)
    return 1.0f - 2.0f * __builtin_amdgcn_rcpf(e + 1.0f); // graceful at +-inf
}

// acc += f16(lo half of SGPR w) * h   -- weight stays in an SGPR, zero VGPR cost
DI float mixlo(unsigned w, float h, float acc){
    asm("v_fma_mix_f32 %0, %1, %2, %0 op_sel:[0,0,0] op_sel_hi:[1,0,0]"
        : "+v"(acc) : "s"(w), "v"(h));
    return acc;
}
// acc += f16(hi half of SGPR w) * h
DI float mixhi(unsigned w, float h, float acc){
    asm("v_fma_mix_f32 %0, %1, %2, %0 op_sel:[1,0,0] op_sel_hi:[1,0,0]"
        : "+v"(acc) : "s"(w), "v"(h));
    return acc;
}

// raw 48B row load (3 x dwordx4) into explicit asm-output VGPRs.
// "=&v" early-clobber: outputs can NEVER be aliased onto another live value
// (this is what defeated the C++-level prefetch in rounds 3-7).
DI void row_load(const short* p, uintx4& r0, uintx4& r1, uintx4& r2){
    unsigned long long a64 = (unsigned long long)p;
    asm volatile(
        "global_load_dwordx4 %0, %3, off\n\t"
        "global_load_dwordx4 %1, %3, off offset:16\n\t"
        "global_load_dwordx4 %2, %3, off offset:32"
        : "=&v"(r0), "=&v"(r1), "=&v"(r2)
        : "v"(a64)
        : "memory");
}

// async global->LDS, 16B per lane; LDS dest must be wave-uniform base + lane*16
DI void gload16(const void* g, void* l) {
    __builtin_amdgcn_global_load_lds(
        (const __attribute__((address_space(1))) unsigned int*)g,
        (__attribute__((address_space(3))) unsigned int*)l, 16, 0, 0);
}

// ---------------- weight repack (convs + packed-f16 Whh in one dispatch) ----------------
// conv layout: Wg[ks][kh][q][n][j]: k = ks*32 + q*8 + j (zero-padded), value = Wc[n][k][kh][kw=1]
DI void repack_one(const float* Wc, const float* bc, short* wdst, float* bdst,
                   int COUT, int CIN, int NT, int i)
{
    int j  = i & 7;
    int t1 = i >> 3;
    int n  = t1 % NT;
    int t2 = t1 / NT;
    int qq = t2 & 3;
    int t3 = t2 >> 2;
    int kh = t3 % 3;
    int ks = t3 / 3;
    int k  = ks*32 + qq*8 + j;
    float v = 0.f;
    if (n < COUT && k < CIN) v = Wc[((n*CIN + k)*3 + kh)*3 + 1]; // kw=1 only (W=1, pad=1)
    wdst[i] = f2bf(v);
    if (i < NT) bdst[i] = (i < COUT) ? bc[i] : 0.f;
}

constexpr int RT1 = 3*224*128;
constexpr int RT2 = RT1 + 3*224*224;
constexpr int RT3 = RT2 + 3*112*224;
constexpr int RT4 = RT3 + 72;          // 72 packed Whh words

__global__ __launch_bounds__(256) void repack_all(
    const float* __restrict__ Wc1, const float* __restrict__ bc1, short* __restrict__ w1, float* __restrict__ b1,
    const float* __restrict__ Wc2, const float* __restrict__ bc2, short* __restrict__ w2, float* __restrict__ b2,
    const float* __restrict__ Wc3, const float* __restrict__ bc3, short* __restrict__ w3, float* __restrict__ b3,
    const float* __restrict__ Whh, unsigned* __restrict__ wh)
{
    int idx = blockIdx.x*256 + threadIdx.x;
    if (idx < RT1)       repack_one(Wc1, bc1, w1, b1, 194,  97, 224, idx);
    else if (idx < RT2)  repack_one(Wc2, bc2, w2, b2, 194, 194, 224, idx - RT1);
    else if (idx < RT3)  repack_one(Wc3, bc3, w3, b3,  97, 194, 112, idx - RT2);
    else if (idx < RT4) {
        int i = idx - RT3;             // 0..71: g = gate row (0..23), dp = d-pair (0..2)
        int g = i / 3, dp = i - g*3;
        unsigned lo = (unsigned short)f2h(Whh[g*6 + 2*dp]);
        unsigned hi = (unsigned short)f2h(Whh[g*6 + 2*dp + 1]);
        wh[i] = lo | (hi << 16);
    }
}

// ---------------- x-projection: f16, plain gate order, LDS-staged coalesced stores ----
__global__ __launch_bounds__(256) void xproj_kernel(
    const float* __restrict__ X, const float* __restrict__ Wih,
    const float* __restrict__ bih, const float* __restrict__ bhh,
    short* __restrict__ xp)
{
    __shared__ alignas(16) short sbuf[256*24];      // 12 KB
    const int tid = threadIdx.x;
    const int idx = blockIdx.x*256 + tid;           // t*97+n, exactly T*97 threads
    const floatx4* xv = (const floatx4*)(X + (size_t)idx*12);
    floatx4 x0 = xv[0], x1 = xv[1], x2 = xv[2];
    float xr[12];
    #pragma unroll
    for (int f=0; f<4; ++f){ xr[f]=x0[f]; xr[4+f]=x1[f]; xr[8+f]=x2[f]; }

    short o24[24];
    #pragma unroll
    for (int g=0; g<24; ++g) {
        float s = bih[g] + bhh[g];
        #pragma unroll
        for (int f=0; f<12; ++f) s = fmaf(xr[f], Wih[g*12+f], s);
        o24[g] = f2h(s);                            // plain order: row g = Whh/bias row g
    }
    #pragma unroll
    for (int k=0; k<3; ++k)
        *(uintx4*)(&sbuf[tid*24 + k*8]) = *(const uintx4*)(&o24[k*8]);
    __syncthreads();
    const size_t base = (size_t)blockIdx.x * (256*24);
    #pragma unroll
    for (int k=0; k<3; ++k) {
        int off = k*2048 + tid*8;                   // shorts; 16B per lane, contiguous
        *(uintx4*)(xp + base + off) = *(const uintx4*)(&sbuf[off]);
    }
}

// ---------------- LSTM: 1 lane = 1 full chain, ISA-level double-buffered stream ----------
// Rounds 3-7 proved the compiler always collapses a C++-level prefetch double-buffer
// (VGPR=24 in r7: cur/nxt aliased into the same 12 regs -> prefetch structurally dead,
// per-step wall 4500cy vs ~900cy issue = pure exposed latency). This version forces
// the double buffer at ISA level: raw global_load_dwordx4 asm with TWO alternating
// "=&v" output sets (A/B -- physically distinct, cannot alias), manual
// s_waitcnt vmcnt(3) (allows the just-issued loads + trailing stores in flight),
// sched_barrier(0) so uses can't hoist above the wait (guide rule #18).
// Weights wave-uniform in 72 SGPRs (f16 pairs) via v_fma_mix -- proven resident.
DI void lstm_step(int s, int ts, bool ch0, const unsigned* w,
                  const uintx4& x0, const uintx4& x1, const uintx4& x2,
                  float* h, float* cs, short* __restrict__ al, int n)
{
    if (s == 0) {                                   // chunk 0 starts from the true init
        #pragma unroll
        for (int j=0;j<6;++j){ h[j] = ch0 ? 0.f : h[j]; cs[j] = ch0 ? 0.f : cs[j]; }
    }
    unsigned cur[12];
    #pragma unroll
    for (int k=0;k<4;++k){ cur[k]=x0[k]; cur[4+k]=x1[k]; cur[8+k]=x2[k]; }

    float hn[6];
    #pragma unroll
    for (int j=0;j<6;++j){
        float gi = (j&1) ? h2f_hi(cur[(j)>>1])    : h2f_lo(cur[(j)>>1]);
        float gf = (j&1) ? h2f_hi(cur[(6+j)>>1])  : h2f_lo(cur[(6+j)>>1]);
        float gc = (j&1) ? h2f_hi(cur[(12+j)>>1]) : h2f_lo(cur[(12+j)>>1]);
        float go = (j&1) ? h2f_hi(cur[(18+j)>>1]) : h2f_lo(cur[(18+j)>>1]);
        #pragma unroll
        for (int dp=0; dp<3; ++dp){
            gi = mixlo(w[(j   )*3+dp], h[2*dp], gi); gi = mixhi(w[(j   )*3+dp], h[2*dp+1], gi);
            gf = mixlo(w[(6+j )*3+dp], h[2*dp], gf); gf = mixhi(w[(6+j )*3+dp], h[2*dp+1], gf);
            gc = mixlo(w[(12+j)*3+dp], h[2*dp], gc); gc = mixhi(w[(12+j)*3+dp], h[2*dp+1], gc);
            go = mixlo(w[(18+j)*3+dp], h[2*dp], go); go = mixhi(w[(18+j)*3+dp], h[2*dp+1], go);
        }
        float ig = fsig(gi), fg = fsig(gf), cg = ftanh(gc), og = fsig(go);
        cs[j] = fmaf(fg, cs[j], ig*cg);
        hn[j] = ftanh(og * ftanh(cs[j]));            // extra tanh, fed back (matches ref)
    }
    #pragma unroll
    for (int j=0;j<6;++j) h[j] = hn[j];

    if (s >= 0) {
        int base = (ts + s)*6*128 + n;               // A[m=(t,j)][k=n], stride 128
        #pragma unroll
        for (int j=0;j<6;++j) al[base + j*128] = f2bf(hn[j]);
    }
}

__global__ __launch_bounds__(256, 1) void lstm_kernel(
    const short* __restrict__ xp, const unsigned* __restrict__ wpk,
    short* __restrict__ al)
{
    const int c  = blockIdx.x*256 + threadIdx.x;    // chain id, 0..99327
    const int ch = c / NN;
    const int n  = c - ch*NN;
    const int ts = ch*CHUNK;
    const bool ch0 = (ch == 0);

    unsigned w[72];                                 // packed f16 pairs, wave-uniform -> SGPRs
    #pragma unroll
    for (int i=0; i<72; i+=4){
        uintx4 v = *(const uintx4*)(wpk + i);
        w[i+0] = __builtin_amdgcn_readfirstlane(v[0]);
        w[i+1] = __builtin_amdgcn_readfirstlane(v[1]);
        w[i+2] = __builtin_amdgcn_readfirstlane(v[2]);
        w[i+3] = __builtin_amdgcn_readfirstlane(v[3]);
    }

    float h[6]  = {0,0,0,0,0,0};
    float cs[6] = {0,0,0,0,0,0};

    const long long RSTR = (long long)NN*24;        // xp row stride in shorts (4656 B)
    const short* p = xp + ((long long)(ts - WARM)*NN + n)*24;  // row of step s=-WARM

    uintx4 A0, A1, A2, B0, B1, B2;
    row_load(p, A0, A1, A2);                        // row for first step

    #pragma unroll 1
    for (int s = -WARM; s < CHUNK; s += 2) {
        // even half: consume A (loaded one step ago), prefetch s+1 into B
        row_load(p + RSTR, B0, B1, B2);
        asm volatile("s_waitcnt vmcnt(3)" ::: "memory");   // A done (B + <=stores in flight... B only)
        __builtin_amdgcn_sched_barrier(0);
        lstm_step(s, ts, ch0, w, A0, A1, A2, h, cs, al, n);

        // odd half: consume B, prefetch s+2 into A
        row_load(p + 2*RSTR, A0, A1, A2);
        asm volatile("s_waitcnt vmcnt(3)" ::: "memory");   // B done (A + stores in flight)
        __builtin_amdgcn_sched_barrier(0);
        lstm_step(s+1, ts, ch0, w, B0, B1, B2, h, cs, al, n);

        p += 2*RSTR;
    }
}

// ---------------- pipelined conv as 3-tap (kh) GEMM, bf16 MFMA 16x16x32 ----------------
// Tile 192 rows x 112 cols, t-group aligned (192 = 32*6) so the +-1 kh halo never
// crosses a tile boundary (h=-1/6 rows are zero via vmask) -> A staging is exactly
// 768 chunks = 3 clean instructions/wave, no halo/tail/zero-page/bounds checks.
// A LDS layout is [row][q^swz] so consecutive chunks are 64B-contiguous per row:
// 16 rows x 64B = 16 cache-line requests per global_load_lds (was 64 with [q][row]).
// Double-buffered A (2x12.3KB) + B (2x21.5KB) = 67.6KB -> 2 blocks/CU; grids
// 1024/1024/512 blocks against 512 resident slots = exact 2/2/1 scheduling rounds.
template<int KP, int NTF, bool STATS>
__global__ __launch_bounds__(256) void conv_pipe(
    const short* __restrict__ In, const short* __restrict__ Wm,
    const float* __restrict__ bias, short* __restrict__ Out,
    float* __restrict__ stats)
{
    constexpr int KS = KP/32;
    constexpr int MR = 192;                         // rows per tile (32 t-groups)
    __shared__ alignas(16) short Abuf[2][MR*4*8];   // 12.3 KB per buffer
    __shared__ alignas(16) short Bbuf[2][1344*8];   // 21.5 KB per buffer
    __shared__ float sst[2][112];

    const int tid   = threadIdx.x;
    const int lane  = tid & 63;
    const int wv    = tid >> 6;
    const int l16   = lane & 15;
    const int q     = lane >> 4;
    const int m0    = blockIdx.x * MR;              // t-group aligned (192 % 6 == 0)
    const int nbase = blockIdx.y * 112;

    if (STATS && tid < 112){ sst[0][tid]=0.f; sst[1][tid]=0.f; }

    auto stageA = [&](int ks, int b) {
        const int k0 = ks*32;
        #pragma unroll
        for (int it=0; it<3; ++it) {                // 768 chunks exactly, all real
            int c  = it*256 + tid;
            int r  = c >> 2;
            int qg = (c & 3) ^ ((r >> 1) & 3);      // bank swizzle (matches read side)
            gload16(In + (size_t)(m0 + r)*KP + k0 + qg*8, &Abuf[b][c*8]);
        }
    };
    auto stageB = [&](int ks, int b) {
        #pragma unroll
        for (int it=0; it<5; ++it) {                // chunks 0..1279
            int c    = it*256 + tid;
            int run  = c / 112;
            int ridx = c - run*112;
            gload16(Wm + ((size_t)(ks*12 + run)*NTF + nbase + ridx)*8, &Bbuf[b][c*8]);
        }
        {                                           // tail 1280..1343, all 4 waves (dup ok)
            int c    = 1280 + (tid & 63);
            int run  = c / 112;
            int ridx = c - run*112;
            gload16(Wm + ((size_t)(ks*12 + run)*NTF + nbase + ridx)*8, &Bbuf[b][c*8]);
        }
    };

    // per-(mf,kh) A validity + swizzled LDS byte-chunk offsets (hoisted)
    bool vmask[3][3];
    int  aoff[3][3];
    #pragma unroll
    for (int mf=0; mf<3; ++mf){
        int mrow = wv*48 + mf*16 + l16;
        int m6 = mrow % 6;                          // m0 % 6 == 0
        #pragma unroll
        for (int kh=0; kh<3; ++kh){
            int hh = m6 + kh - 1;
            vmask[mf][kh] = (hh >= 0) && (hh < 6);
            int rr = mrow + kh - 1;
            rr = rr < 0 ? 0 : (rr > MR-1 ? MR-1 : rr);  // clamp (value discarded via vmask)
            aoff[mf][kh] = (rr*4 + (q ^ ((rr >> 1) & 3)))*8;
        }
    }

    floatx4 acc[3][7];
    #pragma unroll
    for (int a=0;a<3;++a)
      #pragma unroll
      for (int b=0;b<7;++b)
        #pragma unroll
        for (int r=0;r<4;++r) acc[a][b][r] = 0.f;

    stageA(0, 0); stageB(0, 0);                     // 9 VMEM issues per wave

    for (int ks = 0; ks < KS; ++ks) {
        const int cur = ks & 1;
        if (ks + 1 < KS) {
            stageA(ks+1, cur^1); stageB(ks+1, cur^1);          // 9 more in flight
            asm volatile("s_waitcnt vmcnt(9)" ::: "memory");   // cur's 9 done
        } else {
            asm volatile("s_waitcnt vmcnt(0)" ::: "memory");
        }
        asm volatile("s_barrier" ::: "memory");     // cur buffer ready for all waves

        #pragma unroll
        for (int kh = 0; kh < 3; ++kh) {
            bf16x8 z = {0,0,0,0,0,0,0,0};
            bf16x8 af[3];
            #pragma unroll
            for (int mf=0; mf<3; ++mf){
                bf16x8 a = *(const bf16x8*)(&Abuf[cur][aoff[mf][kh]]);
                af[mf] = vmask[mf][kh] ? a : z;
            }
            const int bbase = (kh*4 + q)*112 + l16;
            #pragma unroll
            for (int nf = 0; nf < 7; ++nf) {
                bf16x8 b = *(const bf16x8*)(&Bbuf[cur][(bbase + nf*16)*8]);
                #pragma unroll
                for (int mf=0; mf<3; ++mf)
                    acc[mf][nf] = __builtin_amdgcn_mfma_f32_16x16x32_bf16(af[mf], b, acc[mf][nf], 0, 0, 0);
            }
        }
        asm volatile("s_barrier" ::: "memory");     // all reads of cur done (WAR for ks+2 staging)
    }

    // epilogue: bias + relu + store bf16 (+ BN partial stats for conv3)
    #pragma unroll
    for (int nf = 0; nf < 7; ++nf) {
        const int col = nbase + nf*16 + l16;
        const float bv = bias[col];
        float s1 = 0.f, s2 = 0.f;
        #pragma unroll
        for (int mf = 0; mf < 3; ++mf) {
            floatx4 v = acc[mf][nf];
            #pragma unroll
            for (int r = 0; r < 4; ++r) {
                float y = fmaxf(v[r] + bv, 0.f);
                const int mg = m0 + wv*48 + mf*16 + q*4 + r; // C/D: row=q*4+r, col=l16
                Out[(size_t)mg*NTF + col] = f2bf(y);
                if (STATS){ s1 += y; s2 += y*y; }
            }
        }
        if (STATS) {
            s1 += __shfl_xor(s1, 16); s1 += __shfl_xor(s1, 32);
            s2 += __shfl_xor(s2, 16); s2 += __shfl_xor(s2, 32);
            if (q == 0 && col < 97) {
                atomicAdd(&sst[0][col], s1);
                atomicAdd(&sst[1][col], s2);
            }
        }
    }
    if (STATS) {
        __syncthreads();
        if (tid < 97) {
            atomicAdd(&stats[tid],     sst[0][tid]);
            atomicAdd(&stats[128+tid], sst[1][tid]);
        }
    }
}

// ---------------- BN (batch stats) + affine + Linear(6,6) + layout transpose ----------------
__global__ __launch_bounds__(256) void final_kernel(
    const short* __restrict__ f3, const float* __restrict__ stats,
    const float* __restrict__ gamma, const float* __restrict__ beta,
    const float* __restrict__ Wl, const float* __restrict__ bl,
    float* __restrict__ out)
{
    const int idx = blockIdx.x*256 + threadIdx.x;  // t*97+n
    const int t = idx / NN;
    const int n = idx - t*NN;
    const float inv_cnt = 1.0f / (float)M_TOT;
    const float mean = stats[n] * inv_cnt;
    const float var  = stats[128+n] * inv_cnt - mean*mean;
    const float rstd = rsqrtf(var + 1e-5f);
    const float ga = gamma[n], be = beta[n];
    float v[6];
    #pragma unroll
    for (int hh=0; hh<6; ++hh) {
        float raw = bf2f(f3[(size_t)(t*6 + hh)*112 + n]);
        v[hh] = (raw - mean)*rstd*ga + be;
    }
    #pragma unroll
    for (int ho=0; ho<6; ++ho) {
        float o = bl[ho];
        #pragma unroll
        for (int hh=0; hh<6; ++hh) o = fmaf(v[hh], Wl[ho*6+hh], o);
        out[(size_t)idx*6 + ho] = o;
    }
}

extern "C" void kernel_launch(void* const* d_in, const int* in_sizes, int n_in,
                              void* d_out, int out_size, void* d_ws, size_t ws_size,
                              hipStream_t stream)
{
    const float* X    = (const float*)d_in[1];
    const float* Wih  = (const float*)d_in[3];
    const float* Whh  = (const float*)d_in[4];
    const float* bih  = (const float*)d_in[5];
    const float* bhh  = (const float*)d_in[6];
    const float* Wc1  = (const float*)d_in[7];
    const float* bc1  = (const float*)d_in[8];
    const float* Wc2  = (const float*)d_in[9];
    const float* bc2  = (const float*)d_in[10];
    const float* Wc3  = (const float*)d_in[11];
    const float* bc3  = (const float*)d_in[12];
    const float* gam  = (const float*)d_in[13];
    const float* bet  = (const float*)d_in[14];
    const float* Wl   = (const float*)d_in[15];
    const float* bl   = (const float*)d_in[16];

    char* ws = (char*)d_ws;
    short* al = (short*)(ws + AL_OFF);
    short* f1 = (short*)(ws + F1_OFF);
    short* f2 = (short*)(ws + F2_OFF);
    short* f3 = (short*)(ws + F3_OFF);
    short* xp = (short*)(ws + XP_OFF);   // aliases f1/f2 (dead before conv1)
    short* w1 = (short*)(ws + W1_OFF);
    short* w2 = (short*)(ws + W2_OFF);
    short* w3 = (short*)(ws + W3_OFF);
    float* b1 = (float*)(ws + B1_OFF);
    float* b2 = (float*)(ws + B2_OFF);
    float* b3 = (float*)(ws + B3_OFF);
    float* st = (float*)(ws + ST_OFF);
    unsigned* wh = (unsigned*)(ws + WH_OFF);

    hipMemsetAsync(al, 0, AL_SZ, stream);       // zero-pad columns 97..127 of al (also the
                                                // in-bounds target of ch==0 warm reads)
    hipMemsetAsync(st, 0, 1024, stream);        // BN stat accumulators

    repack_all<<<(RT4+255)/256, 256, 0, stream>>>(Wc1, bc1, w1, b1,
                                                  Wc2, bc2, w2, b2,
                                                  Wc3, bc3, w3, b3,
                                                  Whh, wh);

    xproj_kernel<<<(T_STEPS*NN)/256, 256, 0, stream>>>(X, Wih, bih, bhh, xp);

    lstm_kernel<<<(NCHUNK*NN)/256, 256, 0, stream>>>(xp, wh, al);

    conv_pipe<128,224,false><<<dim3(M_TOT/192, 2), 256, 0, stream>>>(al, w1, b1, f1, nullptr);
    conv_pipe<224,224,false><<<dim3(M_TOT/192, 2), 256, 0, stream>>>(f1, w2, b2, f2, nullptr);
    conv_pipe<224,112,true ><<<dim3(M_TOT/192, 1), 256, 0, stream>>>(f2, w3, b3, f3, st);

    final_kernel<<<(T_STEPS*NN)/256, 256, 0, stream>>>(f3, st, gam, bet, Wl, bl, (float*)d_out);
}